// Round 1
// baseline (642.653 us; speedup 1.0000x reference)
//
#include <hip/hip_runtime.h>
#include <cstdint>
#include <cstddef>

#define B_    64
#define P_    24564
#define C_    81
#define NOBJ_ 16
#define SLICE_ 1536   // ceil(P_/16)

__device__ __forceinline__ float smooth_l1(float d){
  float ad = fabsf(d);
  return (ad < 1.0f) ? 0.5f * d * d : ad - 0.5f;
}

// ---------------- init: zero accumulators ----------------
__global__ void k_init(unsigned long long* packed, int* n_pos, int* total_pos, float* accs){
  int i = blockIdx.x * blockDim.x + threadIdx.x;
  if (i < B_ * NOBJ_) packed[i] = 0ull;
  if (i < B_) n_pos[i] = 0;
  if (i < 3) accs[i] = 0.f;
  if (i == 0) *total_pos = 0;
}

// ---------------- phase 1: per-object best prior ----------------
// packed[b][o] = (float_bits(best_iou) << 32) | (0xFFFFFFFF - best_prior_idx)
// atomicMax => max IoU, ties resolved to smallest prior index (np.argmax first-wins)
__global__ __launch_bounds__(256) void k_match1(const float* __restrict__ boxes,
                                                const float* __restrict__ priors,
                                                unsigned long long* __restrict__ packed){
  const int b = blockIdx.x, slice = blockIdx.y, tid = threadIdx.x;
  __shared__ float sb[NOBJ_ * 4];
  __shared__ float sba[NOBJ_];
  if (tid < NOBJ_ * 4) sb[tid] = boxes[b * NOBJ_ * 4 + tid];
  __syncthreads();
  if (tid < NOBJ_) sba[tid] = (sb[tid*4+2] - sb[tid*4+0]) * (sb[tid*4+3] - sb[tid*4+1]);
  __syncthreads();

  float bv[NOBJ_]; int bi[NOBJ_];
  #pragma unroll
  for (int o = 0; o < NOBJ_; ++o){ bv[o] = -1.f; bi[o] = 0x7FFFFFFF; }

  const int p0 = slice * SLICE_;
  for (int k = 0; k < SLICE_ / 256; ++k){
    int p = p0 + k * 256 + tid;
    if (p < P_){
      float4 pr = reinterpret_cast<const float4*>(priors)[p];
      float px0 = pr.x - pr.z / 2.f, py0 = pr.y - pr.w / 2.f;
      float px1 = pr.x + pr.z / 2.f, py1 = pr.y + pr.w / 2.f;
      float pa  = (px1 - px0) * (py1 - py0);
      #pragma unroll
      for (int o = 0; o < NOBJ_; ++o){
        float ix = fminf(sb[o*4+2], px1) - fmaxf(sb[o*4+0], px0);
        float iy = fminf(sb[o*4+3], py1) - fmaxf(sb[o*4+1], py0);
        ix = fmaxf(ix, 0.f); iy = fmaxf(iy, 0.f);
        float inter = ix * iy;
        float v = inter / (sba[o] + pa - inter);
        if (v > bv[o] || (v == bv[o] && p < bi[o])){ bv[o] = v; bi[o] = p; }
      }
    }
  }

  // wave reduce (64 lanes)
  const int lane = tid & 63, wid = tid >> 6;
  #pragma unroll
  for (int o = 0; o < NOBJ_; ++o){
    for (int off = 32; off; off >>= 1){
      float v2 = __shfl_down(bv[o], off);
      int   i2 = __shfl_down(bi[o], off);
      if (v2 > bv[o] || (v2 == bv[o] && i2 < bi[o])){ bv[o] = v2; bi[o] = i2; }
    }
  }
  __shared__ float rv[4][NOBJ_];
  __shared__ int   ri[4][NOBJ_];
  if (lane == 0){
    #pragma unroll
    for (int o = 0; o < NOBJ_; ++o){ rv[wid][o] = bv[o]; ri[wid][o] = bi[o]; }
  }
  __syncthreads();
  if (tid < NOBJ_){
    float v = rv[0][tid]; int i = ri[0][tid];
    #pragma unroll
    for (int w = 1; w < 4; ++w){
      float v2 = rv[w][tid]; int i2 = ri[w][tid];
      if (v2 > v || (v2 == v && i2 < i)){ v = v2; i = i2; }
    }
    if (v >= 0.f){
      unsigned long long pk = ((unsigned long long)__float_as_uint(v) << 32)
                            | (unsigned long long)(0xFFFFFFFFu - (unsigned)i);
      atomicMax(&packed[b * NOBJ_ + tid], pk);
    }
  }
}

// ---------------- phase 2: per-prior match, labels, loc loss ----------------
__global__ __launch_bounds__(256) void k_match2(const float* __restrict__ boxes,
                                                const int*   __restrict__ labels,
                                                const float* __restrict__ priors,
                                                const float* __restrict__ pred_locs,
                                                const unsigned long long* __restrict__ packed,
                                                int* __restrict__ true_classes,
                                                int* __restrict__ n_pos,
                                                int* __restrict__ total_pos,
                                                float* __restrict__ accs){
  const int b = blockIdx.x, slice = blockIdx.y, tid = threadIdx.x;
  __shared__ float sb[NOBJ_ * 4];
  __shared__ float sba[NOBJ_];
  __shared__ int   slab[NOBJ_];
  __shared__ int   sppo[NOBJ_];
  if (tid < NOBJ_ * 4) sb[tid] = boxes[b * NOBJ_ * 4 + tid];
  if (tid < NOBJ_){
    slab[tid] = labels[b * NOBJ_ + tid];
    unsigned long long pk = packed[b * NOBJ_ + tid];
    sppo[tid] = (int)(0xFFFFFFFFu - (unsigned)(pk & 0xFFFFFFFFull));
  }
  __syncthreads();
  if (tid < NOBJ_) sba[tid] = (sb[tid*4+2] - sb[tid*4+0]) * (sb[tid*4+3] - sb[tid*4+1]);
  __syncthreads();

  int cnt = 0; float sl1 = 0.f;
  const int p0 = slice * SLICE_;
  for (int k = 0; k < SLICE_ / 256; ++k){
    int p = p0 + k * 256 + tid;
    if (p < P_){
      float4 pr = reinterpret_cast<const float4*>(priors)[p];
      float px0 = pr.x - pr.z / 2.f, py0 = pr.y - pr.w / 2.f;
      float px1 = pr.x + pr.z / 2.f, py1 = pr.y + pr.w / 2.f;
      float pa  = (px1 - px0) * (py1 - py0);
      float mx = -1.f; int am = 0;
      #pragma unroll
      for (int o = 0; o < NOBJ_; ++o){
        float ix = fminf(sb[o*4+2], px1) - fmaxf(sb[o*4+0], px0);
        float iy = fminf(sb[o*4+3], py1) - fmaxf(sb[o*4+1], py0);
        ix = fmaxf(ix, 0.f); iy = fmaxf(iy, 0.f);
        float inter = ix * iy;
        float v = inter / (sba[o] + pa - inter);
        if (v > mx){ mx = v; am = o; }   // first-wins (strict >)
      }
      // forced matches: ascending o => numpy last-write-wins on duplicates
      #pragma unroll
      for (int o = 0; o < NOBJ_; ++o){
        if (sppo[o] == p){ am = o; mx = 1.0f; }
      }
      int lab = slab[am];
      if (mx < 0.5f) lab = 0;
      true_classes[(size_t)b * P_ + p] = lab;
      if (lab != 0){
        ++cnt;
        float x0 = sb[am*4+0], y0 = sb[am*4+1], x1 = sb[am*4+2], y1 = sb[am*4+3];
        float cx = (x0 + x1) / 2.f, cy = (y0 + y1) / 2.f;
        float w_  = x1 - x0, h_ = y1 - y0;
        float g0 = (cx - pr.x) / (pr.z / 10.0f);
        float g1 = (cy - pr.y) / (pr.w / 10.0f);
        float g2 = logf(w_ / pr.z) * 5.0f;
        float g3 = logf(h_ / pr.w) * 5.0f;
        float4 pl = reinterpret_cast<const float4*>(pred_locs)[(size_t)b * P_ + p];
        sl1 += smooth_l1(pl.x - g0) + smooth_l1(pl.y - g1)
             + smooth_l1(pl.z - g2) + smooth_l1(pl.w - g3);
      }
    }
  }
  // block reduce
  for (int off = 32; off; off >>= 1){
    cnt += __shfl_down(cnt, off);
    sl1 += __shfl_down(sl1, off);
  }
  __shared__ int   rc[4];
  __shared__ float rs[4];
  const int lane = tid & 63, wid = tid >> 6;
  if (lane == 0){ rc[wid] = cnt; rs[wid] = sl1; }
  __syncthreads();
  if (tid == 0){
    int c = 0; float s = 0.f;
    for (int w = 0; w < 4; ++w){ c += rc[w]; s += rs[w]; }
    atomicAdd(&n_pos[b], c);
    atomicAdd(total_pos, c);
    atomicAdd(&accs[0], s);   // sl1 sum
  }
}

// ---------------- CE: one wave per (b,p) row ----------------
__global__ __launch_bounds__(256) void k_ce(const float* __restrict__ scores,
                                            const int*   __restrict__ tc,
                                            float* __restrict__ ce_neg,
                                            float* __restrict__ conf_pos){
  const int tid = threadIdx.x, lane = tid & 63, wid = tid >> 6;
  const long long row = (long long)blockIdx.x * 4 + wid;
  if (row >= (long long)B_ * P_) return;
  const float* sc = scores + (size_t)row * C_;
  float s0 = sc[lane];
  float s1 = (lane < C_ - 64) ? sc[64 + lane] : -3.0e38f;
  float m = fmaxf(s0, s1);
  #pragma unroll
  for (int off = 32; off; off >>= 1) m = fmaxf(m, __shfl_xor(m, off));
  float e = expf(s0 - m);
  if (lane < C_ - 64) e += expf(s1 - m);
  #pragma unroll
  for (int off = 32; off; off >>= 1) e += __shfl_xor(e, off);
  if (lane == 0){
    int t = tc[row];
    float ce = logf(e) + m - sc[t];
    if (t != 0){
      atomicAdd(conf_pos, ce);
      ce_neg[row] = 0.f;
    } else {
      ce_neg[row] = fmaxf(ce, 0.f);
    }
  }
}

// ---------------- per-image exact top-K sum via radix select ----------------
__global__ __launch_bounds__(256) void k_topk(const float* __restrict__ ce_neg,
                                              const int*   __restrict__ n_pos,
                                              float* __restrict__ hard_acc){
  const int b = blockIdx.x, tid = threadIdx.x;
  const float* v = ce_neg + (size_t)b * P_;
  const int K = 3 * n_pos[b];
  if (K <= 0) return;

  __shared__ int hist[256];
  __shared__ unsigned s_prefix;
  __shared__ int s_rem;
  __shared__ float rsum[4];
  const int lane = tid & 63, wid = tid >> 6;

  if (K >= P_){
    float s = 0.f;
    for (int p = tid; p < P_; p += 256) s += v[p];
    for (int off = 32; off; off >>= 1) s += __shfl_down(s, off);
    if (lane == 0) rsum[wid] = s;
    __syncthreads();
    if (tid == 0){
      float t = 0.f;
      for (int w = 0; w < 4; ++w) t += rsum[w];
      atomicAdd(hard_acc, t);
    }
    return;
  }

  unsigned prefix = 0; int remaining = K;
  for (int shift = 24; shift >= 0; shift -= 8){
    hist[tid] = 0;
    __syncthreads();
    unsigned hmask = (shift == 24) ? 0u : (0xFFFFFFFFu << (shift + 8));
    for (int p = tid; p < P_; p += 256){
      unsigned u = __float_as_uint(v[p]);
      if ((u & hmask) == prefix) atomicAdd(&hist[(u >> shift) & 255], 1);
    }
    __syncthreads();
    if (tid == 0){
      int cum = 0, sel = 0;
      for (int bin = 255; bin >= 0; --bin){
        int c = hist[bin];
        if (cum + c >= remaining){ sel = bin; break; }
        cum += c;
      }
      s_prefix = prefix | ((unsigned)sel << shift);
      s_rem = remaining - cum;
    }
    __syncthreads();
    prefix = s_prefix;
    remaining = s_rem;
    __syncthreads();
  }

  float t = __uint_as_float(prefix);
  float sgt = 0.f;
  for (int p = tid; p < P_; p += 256){
    unsigned u = __float_as_uint(v[p]);
    if (u > prefix) sgt += v[p];
  }
  for (int off = 32; off; off >>= 1) sgt += __shfl_down(sgt, off);
  if (lane == 0) rsum[wid] = sgt;
  __syncthreads();
  if (tid == 0){
    float s = 0.f;
    for (int w = 0; w < 4; ++w) s += rsum[w];
    atomicAdd(hard_acc, s + (float)remaining * t);
  }
}

// ---------------- final combine ----------------
__global__ void k_final(const float* __restrict__ accs, const int* __restrict__ total_pos,
                        float* __restrict__ out){
  float tp = (float)(*total_pos);
  float conf = (accs[2] + accs[1]) / tp;       // (hard_neg + pos) / total_pos
  float loc  = accs[0] / (tp * 4.0f);          // sl1_sum / (total_pos*4)
  out[0] = conf + loc;
}

extern "C" void kernel_launch(void* const* d_in, const int* in_sizes, int n_in,
                              void* d_out, int out_size, void* d_ws, size_t ws_size,
                              hipStream_t stream){
  const float* pred_locs = (const float*)d_in[0];
  const float* scores    = (const float*)d_in[1];
  const float* boxes     = (const float*)d_in[2];
  const int*   labels    = (const int*)d_in[3];
  const float* priors    = (const float*)d_in[4];

  const size_t BP = (size_t)B_ * P_;
  char* w = (char*)d_ws;
  int*   true_classes = (int*)w;                              // BP int32
  float* ce_neg       = (float*)(w + BP * 4);                 // BP f32
  unsigned long long* packed = (unsigned long long*)(w + 2 * BP * 4);  // B*NOBJ u64
  int*   n_pos     = (int*)(w + 2 * BP * 4 + B_ * NOBJ_ * 8); // B int
  int*   total_pos = n_pos + B_;                              // 1 int
  float* accs      = (float*)(total_pos + 1);                 // [sl1, conf_pos, hard]

  k_init<<<4, 256, 0, stream>>>(packed, n_pos, total_pos, accs);

  dim3 g1(B_, 16);
  k_match1<<<g1, 256, 0, stream>>>(boxes, priors, packed);
  k_match2<<<g1, 256, 0, stream>>>(boxes, labels, priors, pred_locs, packed,
                                   true_classes, n_pos, total_pos, accs);

  int blocks_ce = (int)((BP + 3) / 4);
  k_ce<<<blocks_ce, 256, 0, stream>>>(scores, true_classes, ce_neg, &accs[1]);

  k_topk<<<B_, 256, 0, stream>>>(ce_neg, n_pos, &accs[2]);

  k_final<<<1, 1, 0, stream>>>(accs, total_pos, (float*)d_out);
}

// Round 2
// 448.749 us; speedup vs baseline: 1.4321x; 1.4321x over previous
//
#include <hip/hip_runtime.h>
#include <cstdint>
#include <cstddef>

#define B_    64
#define P_    24564
#define C_    81
#define NOBJ_ 16
#define SLICE_ 1536   // ceil(P_/16)

__device__ __forceinline__ float smooth_l1(float d){
  float ad = fabsf(d);
  return (ad < 1.0f) ? 0.5f * d * d : ad - 0.5f;
}

// ---------------- init: zero accumulators ----------------
__global__ void k_init(unsigned long long* packed, int* n_pos, int* total_pos, float* accs){
  int i = blockIdx.x * blockDim.x + threadIdx.x;
  if (i < B_ * NOBJ_) packed[i] = 0ull;
  if (i < B_) n_pos[i] = 0;
  if (i < 3) accs[i] = 0.f;
  if (i == 0) *total_pos = 0;
}

// ---------------- phase 1: per-object best prior ----------------
// packed[b][o] = (float_bits(best_iou) << 32) | (0xFFFFFFFF - best_prior_idx)
// atomicMax => max IoU, ties resolved to smallest prior index (np.argmax first-wins)
__global__ __launch_bounds__(256) void k_match1(const float* __restrict__ boxes,
                                                const float* __restrict__ priors,
                                                unsigned long long* __restrict__ packed){
  const int b = blockIdx.x, slice = blockIdx.y, tid = threadIdx.x;
  __shared__ float sb[NOBJ_ * 4];
  __shared__ float sba[NOBJ_];
  if (tid < NOBJ_ * 4) sb[tid] = boxes[b * NOBJ_ * 4 + tid];
  __syncthreads();
  if (tid < NOBJ_) sba[tid] = (sb[tid*4+2] - sb[tid*4+0]) * (sb[tid*4+3] - sb[tid*4+1]);
  __syncthreads();

  float bv[NOBJ_]; int bi[NOBJ_];
  #pragma unroll
  for (int o = 0; o < NOBJ_; ++o){ bv[o] = -1.f; bi[o] = 0x7FFFFFFF; }

  const int p0 = slice * SLICE_;
  for (int k = 0; k < SLICE_ / 256; ++k){
    int p = p0 + k * 256 + tid;
    if (p < P_){
      float4 pr = reinterpret_cast<const float4*>(priors)[p];
      float px0 = pr.x - pr.z / 2.f, py0 = pr.y - pr.w / 2.f;
      float px1 = pr.x + pr.z / 2.f, py1 = pr.y + pr.w / 2.f;
      float pa  = (px1 - px0) * (py1 - py0);
      #pragma unroll
      for (int o = 0; o < NOBJ_; ++o){
        float ix = fminf(sb[o*4+2], px1) - fmaxf(sb[o*4+0], px0);
        float iy = fminf(sb[o*4+3], py1) - fmaxf(sb[o*4+1], py0);
        ix = fmaxf(ix, 0.f); iy = fmaxf(iy, 0.f);
        float inter = ix * iy;
        float v = inter / (sba[o] + pa - inter);
        if (v > bv[o] || (v == bv[o] && p < bi[o])){ bv[o] = v; bi[o] = p; }
      }
    }
  }

  // wave reduce (64 lanes)
  const int lane = tid & 63, wid = tid >> 6;
  #pragma unroll
  for (int o = 0; o < NOBJ_; ++o){
    for (int off = 32; off; off >>= 1){
      float v2 = __shfl_down(bv[o], off);
      int   i2 = __shfl_down(bi[o], off);
      if (v2 > bv[o] || (v2 == bv[o] && i2 < bi[o])){ bv[o] = v2; bi[o] = i2; }
    }
  }
  __shared__ float rv[4][NOBJ_];
  __shared__ int   ri[4][NOBJ_];
  if (lane == 0){
    #pragma unroll
    for (int o = 0; o < NOBJ_; ++o){ rv[wid][o] = bv[o]; ri[wid][o] = bi[o]; }
  }
  __syncthreads();
  if (tid < NOBJ_){
    float v = rv[0][tid]; int i = ri[0][tid];
    #pragma unroll
    for (int w = 1; w < 4; ++w){
      float v2 = rv[w][tid]; int i2 = ri[w][tid];
      if (v2 > v || (v2 == v && i2 < i)){ v = v2; i = i2; }
    }
    if (v >= 0.f){
      unsigned long long pk = ((unsigned long long)__float_as_uint(v) << 32)
                            | (unsigned long long)(0xFFFFFFFFu - (unsigned)i);
      atomicMax(&packed[b * NOBJ_ + tid], pk);
    }
  }
}

// ---------------- phase 2: per-prior match, labels, loc loss ----------------
__global__ __launch_bounds__(256) void k_match2(const float* __restrict__ boxes,
                                                const int*   __restrict__ labels,
                                                const float* __restrict__ priors,
                                                const float* __restrict__ pred_locs,
                                                const unsigned long long* __restrict__ packed,
                                                int* __restrict__ true_classes,
                                                int* __restrict__ n_pos,
                                                int* __restrict__ total_pos,
                                                float* __restrict__ accs){
  const int b = blockIdx.x, slice = blockIdx.y, tid = threadIdx.x;
  __shared__ float sb[NOBJ_ * 4];
  __shared__ float sba[NOBJ_];
  __shared__ int   slab[NOBJ_];
  __shared__ int   sppo[NOBJ_];
  if (tid < NOBJ_ * 4) sb[tid] = boxes[b * NOBJ_ * 4 + tid];
  if (tid < NOBJ_){
    slab[tid] = labels[b * NOBJ_ + tid];
    unsigned long long pk = packed[b * NOBJ_ + tid];
    sppo[tid] = (int)(0xFFFFFFFFu - (unsigned)(pk & 0xFFFFFFFFull));
  }
  __syncthreads();
  if (tid < NOBJ_) sba[tid] = (sb[tid*4+2] - sb[tid*4+0]) * (sb[tid*4+3] - sb[tid*4+1]);
  __syncthreads();

  int cnt = 0; float sl1 = 0.f;
  const int p0 = slice * SLICE_;
  for (int k = 0; k < SLICE_ / 256; ++k){
    int p = p0 + k * 256 + tid;
    if (p < P_){
      float4 pr = reinterpret_cast<const float4*>(priors)[p];
      float px0 = pr.x - pr.z / 2.f, py0 = pr.y - pr.w / 2.f;
      float px1 = pr.x + pr.z / 2.f, py1 = pr.y + pr.w / 2.f;
      float pa  = (px1 - px0) * (py1 - py0);
      float mx = -1.f; int am = 0;
      #pragma unroll
      for (int o = 0; o < NOBJ_; ++o){
        float ix = fminf(sb[o*4+2], px1) - fmaxf(sb[o*4+0], px0);
        float iy = fminf(sb[o*4+3], py1) - fmaxf(sb[o*4+1], py0);
        ix = fmaxf(ix, 0.f); iy = fmaxf(iy, 0.f);
        float inter = ix * iy;
        float v = inter / (sba[o] + pa - inter);
        if (v > mx){ mx = v; am = o; }   // first-wins (strict >)
      }
      // forced matches: ascending o => numpy last-write-wins on duplicates
      #pragma unroll
      for (int o = 0; o < NOBJ_; ++o){
        if (sppo[o] == p){ am = o; mx = 1.0f; }
      }
      int lab = slab[am];
      if (mx < 0.5f) lab = 0;
      true_classes[(size_t)b * P_ + p] = lab;
      if (lab != 0){
        ++cnt;
        float x0 = sb[am*4+0], y0 = sb[am*4+1], x1 = sb[am*4+2], y1 = sb[am*4+3];
        float cx = (x0 + x1) / 2.f, cy = (y0 + y1) / 2.f;
        float w_  = x1 - x0, h_ = y1 - y0;
        float g0 = (cx - pr.x) / (pr.z / 10.0f);
        float g1 = (cy - pr.y) / (pr.w / 10.0f);
        float g2 = logf(w_ / pr.z) * 5.0f;
        float g3 = logf(h_ / pr.w) * 5.0f;
        float4 pl = reinterpret_cast<const float4*>(pred_locs)[(size_t)b * P_ + p];
        sl1 += smooth_l1(pl.x - g0) + smooth_l1(pl.y - g1)
             + smooth_l1(pl.z - g2) + smooth_l1(pl.w - g3);
      }
    }
  }
  // block reduce
  for (int off = 32; off; off >>= 1){
    cnt += __shfl_down(cnt, off);
    sl1 += __shfl_down(sl1, off);
  }
  __shared__ int   rc[4];
  __shared__ float rs[4];
  const int lane = tid & 63, wid = tid >> 6;
  if (lane == 0){ rc[wid] = cnt; rs[wid] = sl1; }
  __syncthreads();
  if (tid == 0){
    int c = 0; float s = 0.f;
    for (int w = 0; w < 4; ++w){ c += rc[w]; s += rs[w]; }
    atomicAdd(&n_pos[b], c);
    atomicAdd(total_pos, c);
    atomicAdd(&accs[0], s);   // sl1 sum
  }
}

// ---------------- CE: thread-per-row, LDS-staged coalesced loads ----------------
// 64-thread block stages 64 rows x 81 f32 (20.7 KB) via float4, then each
// thread computes log(sum exp(s)) - s_t over its own row from LDS.
// Stride 81 (odd) => bank = (17*t + j) mod 32, 2 lanes/bank max = conflict-free.
__global__ __launch_bounds__(64) void k_ce(const float* __restrict__ scores,
                                           const int*   __restrict__ tc,
                                           float* __restrict__ ce_neg,
                                           float* __restrict__ conf_pos){
  __shared__ float s[64 * C_];   // 5184 floats = 20736 B
  const int tid = threadIdx.x;
  const size_t row0 = (size_t)blockIdx.x * 64;

  const float4* src = reinterpret_cast<const float4*>(scores + row0 * C_);
  float4* dst = reinterpret_cast<float4*>(s);
  #pragma unroll
  for (int k = 0; k < 20; ++k) dst[k * 64 + tid] = src[k * 64 + tid];
  if (tid < 16) dst[20 * 64 + tid] = src[20 * 64 + tid];
  __syncthreads();

  const float* r = s + tid * C_;
  float sum = 0.f;
  #pragma unroll
  for (int j = 0; j < C_; ++j) sum += __expf(r[j]);

  const int t = tc[row0 + tid];
  const float ce = __logf(sum) - r[t];

  float pos = 0.f, neg;
  if (t != 0){ pos = ce; neg = 0.f; }
  else       { neg = fmaxf(ce, 0.f); }
  ce_neg[row0 + tid] = neg;

  #pragma unroll
  for (int off = 32; off; off >>= 1) pos += __shfl_down(pos, off);
  if (tid == 0 && pos != 0.f) atomicAdd(conf_pos, pos);
}

// ---------------- per-image exact top-K sum via radix select ----------------
__global__ __launch_bounds__(256) void k_topk(const float* __restrict__ ce_neg,
                                              const int*   __restrict__ n_pos,
                                              float* __restrict__ hard_acc){
  const int b = blockIdx.x, tid = threadIdx.x;
  const float* v = ce_neg + (size_t)b * P_;
  const int K = 3 * n_pos[b];
  if (K <= 0) return;

  __shared__ int hist[256];
  __shared__ unsigned s_prefix;
  __shared__ int s_rem;
  __shared__ float rsum[4];
  const int lane = tid & 63, wid = tid >> 6;

  if (K >= P_){
    float s = 0.f;
    for (int p = tid; p < P_; p += 256) s += v[p];
    for (int off = 32; off; off >>= 1) s += __shfl_down(s, off);
    if (lane == 0) rsum[wid] = s;
    __syncthreads();
    if (tid == 0){
      float t = 0.f;
      for (int w = 0; w < 4; ++w) t += rsum[w];
      atomicAdd(hard_acc, t);
    }
    return;
  }

  unsigned prefix = 0; int remaining = K;
  for (int shift = 24; shift >= 0; shift -= 8){
    hist[tid] = 0;
    __syncthreads();
    unsigned hmask = (shift == 24) ? 0u : (0xFFFFFFFFu << (shift + 8));
    for (int p = tid; p < P_; p += 256){
      unsigned u = __float_as_uint(v[p]);
      if ((u & hmask) == prefix) atomicAdd(&hist[(u >> shift) & 255], 1);
    }
    __syncthreads();
    if (tid == 0){
      int cum = 0, sel = 0;
      for (int bin = 255; bin >= 0; --bin){
        int c = hist[bin];
        if (cum + c >= remaining){ sel = bin; break; }
        cum += c;
      }
      s_prefix = prefix | ((unsigned)sel << shift);
      s_rem = remaining - cum;
    }
    __syncthreads();
    prefix = s_prefix;
    remaining = s_rem;
    __syncthreads();
  }

  float t = __uint_as_float(prefix);
  float sgt = 0.f;
  for (int p = tid; p < P_; p += 256){
    unsigned u = __float_as_uint(v[p]);
    if (u > prefix) sgt += v[p];
  }
  for (int off = 32; off; off >>= 1) sgt += __shfl_down(sgt, off);
  if (lane == 0) rsum[wid] = sgt;
  __syncthreads();
  if (tid == 0){
    float s = 0.f;
    for (int w = 0; w < 4; ++w) s += rsum[w];
    atomicAdd(hard_acc, s + (float)remaining * t);
  }
}

// ---------------- final combine ----------------
__global__ void k_final(const float* __restrict__ accs, const int* __restrict__ total_pos,
                        float* __restrict__ out){
  float tp = (float)(*total_pos);
  float conf = (accs[2] + accs[1]) / tp;       // (hard_neg + pos) / total_pos
  float loc  = accs[0] / (tp * 4.0f);          // sl1_sum / (total_pos*4)
  out[0] = conf + loc;
}

extern "C" void kernel_launch(void* const* d_in, const int* in_sizes, int n_in,
                              void* d_out, int out_size, void* d_ws, size_t ws_size,
                              hipStream_t stream){
  const float* pred_locs = (const float*)d_in[0];
  const float* scores    = (const float*)d_in[1];
  const float* boxes     = (const float*)d_in[2];
  const int*   labels    = (const int*)d_in[3];
  const float* priors    = (const float*)d_in[4];

  const size_t BP = (size_t)B_ * P_;
  char* w = (char*)d_ws;
  int*   true_classes = (int*)w;                              // BP int32
  float* ce_neg       = (float*)(w + BP * 4);                 // BP f32
  unsigned long long* packed = (unsigned long long*)(w + 2 * BP * 4);  // B*NOBJ u64
  int*   n_pos     = (int*)(w + 2 * BP * 4 + B_ * NOBJ_ * 8); // B int
  int*   total_pos = n_pos + B_;                              // 1 int
  float* accs      = (float*)(total_pos + 1);                 // [sl1, conf_pos, hard]

  k_init<<<4, 256, 0, stream>>>(packed, n_pos, total_pos, accs);

  dim3 g1(B_, 16);
  k_match1<<<g1, 256, 0, stream>>>(boxes, priors, packed);
  k_match2<<<g1, 256, 0, stream>>>(boxes, labels, priors, pred_locs, packed,
                                   true_classes, n_pos, total_pos, accs);

  // 64 rows per 64-thread block; B_*P_ = 1,572,096 = 24564 * 64 exactly
  k_ce<<<(int)(BP / 64), 64, 0, stream>>>(scores, true_classes, ce_neg, &accs[1]);

  k_topk<<<B_, 256, 0, stream>>>(ce_neg, n_pos, &accs[2]);

  k_final<<<1, 1, 0, stream>>>(accs, total_pos, (float*)d_out);
}

// Round 4
// 257.521 us; speedup vs baseline: 2.4955x; 1.7426x over previous
//
#include <hip/hip_runtime.h>
#include <cstdint>
#include <cstddef>

#define B_    64
#define P_    24564
#define C_    81
#define NOBJ_ 16
#define SLICE_ 1536   // ceil(P_/16)

__device__ __forceinline__ float smooth_l1(float d){
  float ad = fabsf(d);
  return (ad < 1.0f) ? 0.5f * d * d : ad - 0.5f;
}

// ---------------- init: zero accumulators ----------------
__global__ void k_init(unsigned long long* packed, int* n_pos, int* total_pos, float* accs){
  int i = blockIdx.x * blockDim.x + threadIdx.x;
  if (i < B_ * NOBJ_) packed[i] = 0ull;
  if (i < B_) n_pos[i] = 0;
  if (i < 3) accs[i] = 0.f;
  if (i == 0) *total_pos = 0;
}

// ---------------- phase 1: per-object best prior ----------------
__global__ __launch_bounds__(256) void k_match1(const float* __restrict__ boxes,
                                                const float* __restrict__ priors,
                                                unsigned long long* __restrict__ packed){
  const int b = blockIdx.x, slice = blockIdx.y, tid = threadIdx.x;
  __shared__ float sb[NOBJ_ * 4];
  __shared__ float sba[NOBJ_];
  if (tid < NOBJ_ * 4) sb[tid] = boxes[b * NOBJ_ * 4 + tid];
  __syncthreads();
  if (tid < NOBJ_) sba[tid] = (sb[tid*4+2] - sb[tid*4+0]) * (sb[tid*4+3] - sb[tid*4+1]);
  __syncthreads();

  float bv[NOBJ_]; int bi[NOBJ_];
  #pragma unroll
  for (int o = 0; o < NOBJ_; ++o){ bv[o] = -1.f; bi[o] = 0x7FFFFFFF; }

  const int p0 = slice * SLICE_;
  for (int k = 0; k < SLICE_ / 256; ++k){
    int p = p0 + k * 256 + tid;
    if (p < P_){
      float4 pr = reinterpret_cast<const float4*>(priors)[p];
      float px0 = pr.x - pr.z / 2.f, py0 = pr.y - pr.w / 2.f;
      float px1 = pr.x + pr.z / 2.f, py1 = pr.y + pr.w / 2.f;
      float pa  = (px1 - px0) * (py1 - py0);
      #pragma unroll
      for (int o = 0; o < NOBJ_; ++o){
        float ix = fminf(sb[o*4+2], px1) - fmaxf(sb[o*4+0], px0);
        float iy = fminf(sb[o*4+3], py1) - fmaxf(sb[o*4+1], py0);
        ix = fmaxf(ix, 0.f); iy = fmaxf(iy, 0.f);
        float inter = ix * iy;
        float v = inter / (sba[o] + pa - inter);
        if (v > bv[o] || (v == bv[o] && p < bi[o])){ bv[o] = v; bi[o] = p; }
      }
    }
  }

  const int lane = tid & 63, wid = tid >> 6;
  #pragma unroll
  for (int o = 0; o < NOBJ_; ++o){
    for (int off = 32; off; off >>= 1){
      float v2 = __shfl_down(bv[o], off);
      int   i2 = __shfl_down(bi[o], off);
      if (v2 > bv[o] || (v2 == bv[o] && i2 < bi[o])){ bv[o] = v2; bi[o] = i2; }
    }
  }
  __shared__ float rv[4][NOBJ_];
  __shared__ int   ri[4][NOBJ_];
  if (lane == 0){
    #pragma unroll
    for (int o = 0; o < NOBJ_; ++o){ rv[wid][o] = bv[o]; ri[wid][o] = bi[o]; }
  }
  __syncthreads();
  if (tid < NOBJ_){
    float v = rv[0][tid]; int i = ri[0][tid];
    #pragma unroll
    for (int w = 1; w < 4; ++w){
      float v2 = rv[w][tid]; int i2 = ri[w][tid];
      if (v2 > v || (v2 == v && i2 < i)){ v = v2; i = i2; }
    }
    if (v >= 0.f){
      unsigned long long pk = ((unsigned long long)__float_as_uint(v) << 32)
                            | (unsigned long long)(0xFFFFFFFFu - (unsigned)i);
      atomicMax(&packed[b * NOBJ_ + tid], pk);
    }
  }
}

// ---------------- phase 2: per-prior match, labels, loc loss ----------------
__global__ __launch_bounds__(256) void k_match2(const float* __restrict__ boxes,
                                                const int*   __restrict__ labels,
                                                const float* __restrict__ priors,
                                                const float* __restrict__ pred_locs,
                                                const unsigned long long* __restrict__ packed,
                                                int* __restrict__ true_classes,
                                                int* __restrict__ n_pos,
                                                int* __restrict__ total_pos,
                                                float* __restrict__ accs){
  const int b = blockIdx.x, slice = blockIdx.y, tid = threadIdx.x;
  __shared__ float sb[NOBJ_ * 4];
  __shared__ float sba[NOBJ_];
  __shared__ int   slab[NOBJ_];
  __shared__ int   sppo[NOBJ_];
  if (tid < NOBJ_ * 4) sb[tid] = boxes[b * NOBJ_ * 4 + tid];
  if (tid < NOBJ_){
    slab[tid] = labels[b * NOBJ_ + tid];
    unsigned long long pk = packed[b * NOBJ_ + tid];
    sppo[tid] = (int)(0xFFFFFFFFu - (unsigned)(pk & 0xFFFFFFFFull));
  }
  __syncthreads();
  if (tid < NOBJ_) sba[tid] = (sb[tid*4+2] - sb[tid*4+0]) * (sb[tid*4+3] - sb[tid*4+1]);
  __syncthreads();

  int cnt = 0; float sl1 = 0.f;
  const int p0 = slice * SLICE_;
  for (int k = 0; k < SLICE_ / 256; ++k){
    int p = p0 + k * 256 + tid;
    if (p < P_){
      float4 pr = reinterpret_cast<const float4*>(priors)[p];
      float px0 = pr.x - pr.z / 2.f, py0 = pr.y - pr.w / 2.f;
      float px1 = pr.x + pr.z / 2.f, py1 = pr.y + pr.w / 2.f;
      float pa  = (px1 - px0) * (py1 - py0);
      float mx = -1.f; int am = 0;
      #pragma unroll
      for (int o = 0; o < NOBJ_; ++o){
        float ix = fminf(sb[o*4+2], px1) - fmaxf(sb[o*4+0], px0);
        float iy = fminf(sb[o*4+3], py1) - fmaxf(sb[o*4+1], py0);
        ix = fmaxf(ix, 0.f); iy = fmaxf(iy, 0.f);
        float inter = ix * iy;
        float v = inter / (sba[o] + pa - inter);
        if (v > mx){ mx = v; am = o; }
      }
      #pragma unroll
      for (int o = 0; o < NOBJ_; ++o){
        if (sppo[o] == p){ am = o; mx = 1.0f; }
      }
      int lab = slab[am];
      if (mx < 0.5f) lab = 0;
      true_classes[(size_t)b * P_ + p] = lab;
      if (lab != 0){
        ++cnt;
        float x0 = sb[am*4+0], y0 = sb[am*4+1], x1 = sb[am*4+2], y1 = sb[am*4+3];
        float cx = (x0 + x1) / 2.f, cy = (y0 + y1) / 2.f;
        float w_  = x1 - x0, h_ = y1 - y0;
        float g0 = (cx - pr.x) / (pr.z / 10.0f);
        float g1 = (cy - pr.y) / (pr.w / 10.0f);
        float g2 = logf(w_ / pr.z) * 5.0f;
        float g3 = logf(h_ / pr.w) * 5.0f;
        float4 pl = reinterpret_cast<const float4*>(pred_locs)[(size_t)b * P_ + p];
        sl1 += smooth_l1(pl.x - g0) + smooth_l1(pl.y - g1)
             + smooth_l1(pl.z - g2) + smooth_l1(pl.w - g3);
      }
    }
  }
  for (int off = 32; off; off >>= 1){
    cnt += __shfl_down(cnt, off);
    sl1 += __shfl_down(sl1, off);
  }
  __shared__ int   rc[4];
  __shared__ float rs[4];
  const int lane = tid & 63, wid = tid >> 6;
  if (lane == 0){ rc[wid] = cnt; rs[wid] = sl1; }
  __syncthreads();
  if (tid == 0){
    int c = 0; float s = 0.f;
    for (int w = 0; w < 4; ++w){ c += rc[w]; s += rs[w]; }
    atomicAdd(&n_pos[b], c);
    atomicAdd(total_pos, c);
    atomicAdd(&accs[0], s);
  }
}

// ---------------- CE: 1-wave persistent block, dbuf global_load_lds pipeline ----
// Block owns 256 rows = 8 tiles x 32 rows. Tile = 32*81*4B = 10368 B = 648
// float4s, staged by 11 global_load_lds_dwordx4 instrs (10 full-wave of 1024 B
// each + 1 with lanes<8). Double-buffered; counted s_waitcnt vmcnt(11) keeps
// the next tile's 11 loads in flight across compute (never drain to 0 in loop).
// Each row split across 2 lanes (41+40 elems), combined via shfl_xor(32).
#define TILE_F 2592   // 32*81 floats per tile

__device__ __forceinline__ void stage_tile(const float* gsrc, float* lds, int lane){
  const float4* s4 = reinterpret_cast<const float4*>(gsrc);
  #pragma unroll
  for (int k = 0; k < 10; ++k){
    __builtin_amdgcn_global_load_lds(
        (const __attribute__((address_space(1))) void*)(s4 + k * 64 + lane),
        (__attribute__((address_space(3))) void*)(lds + k * 256), 16, 0, 0);
  }
  if (lane < 8)
    __builtin_amdgcn_global_load_lds(
        (const __attribute__((address_space(1))) void*)(s4 + 640 + lane),
        (__attribute__((address_space(3))) void*)(lds + 2560), 16, 0, 0);
}

__device__ __forceinline__ float tile_compute(const float* lbuf, const int* stc, int t,
                                              int lane, size_t row0,
                                              float* __restrict__ ce_neg){
  const int r = lane & 31, h = lane >> 5;
  const int base = r * 81 + h * 41;   // h0: 0..40 (41 elems), h1: 41..80 (40 elems)
  float sum = 0.f;
  #pragma unroll
  for (int j = 0; j < 40; ++j) sum += __expf(lbuf[base + j]);
  if (!h) sum += __expf(lbuf[base + 40]);
  sum += __shfl_xor(sum, 32);
  float pos = 0.f;
  if (!h){
    int cls = stc[t * 32 + r];
    float ce = __logf(sum) - lbuf[r * 81 + cls];
    float neg;
    if (cls != 0){ pos = ce; neg = 0.f; }
    else         { neg = fmaxf(ce, 0.f); }
    ce_neg[row0 + (size_t)t * 32 + r] = neg;
  }
  return pos;
}

__global__ __launch_bounds__(64) void k_ce(const float* __restrict__ scores,
                                           const int*   __restrict__ tc,
                                           float* __restrict__ ce_neg,
                                           float* __restrict__ conf_pos){
  __shared__ float sM[2 * TILE_F];
  __shared__ int   stc[256];
  const int lane = threadIdx.x;
  const size_t row0 = (size_t)blockIdx.x * 256;

  // stage the 256 class ids once (compute phase then has no global loads)
  reinterpret_cast<int4*>(stc)[lane] = reinterpret_cast<const int4*>(tc + row0)[lane];
  __syncthreads();   // drains vmcnt/lgkmcnt before any gload_lds is issued

  const float* g0 = scores + row0 * (size_t)C_;
  stage_tile(g0, sM, lane);
  float posacc = 0.f;
  int buf = 0;
  for (int t = 0; t < 7; ++t){
    stage_tile(g0 + (size_t)(t + 1) * TILE_F, sM + (buf ^ 1) * TILE_F, lane);
    asm volatile("s_waitcnt vmcnt(11)" ::: "memory");  // tile t ready; t+1 in flight
    posacc += tile_compute(sM + buf * TILE_F, stc, t, lane, row0, ce_neg);
    buf ^= 1;
  }
  asm volatile("s_waitcnt vmcnt(0)" ::: "memory");
  posacc += tile_compute(sM + buf * TILE_F, stc, 7, lane, row0, ce_neg);

  #pragma unroll
  for (int off = 16; off; off >>= 1) posacc += __shfl_down(posacc, off);
  if (lane == 0 && posacc != 0.f) atomicAdd(conf_pos, posacc);
}

// ---------------- per-image exact top-K sum via radix select ----------------
__global__ __launch_bounds__(1024) void k_topk(const float* __restrict__ ce_neg,
                                               const int*   __restrict__ n_pos,
                                               float* __restrict__ hard_acc){
  const int b = blockIdx.x, tid = threadIdx.x;
  const float* v = ce_neg + (size_t)b * P_;
  const int K = 3 * n_pos[b];
  if (K <= 0) return;

  __shared__ int histw[16][256];
  __shared__ int histT[256];
  __shared__ unsigned s_prefix;
  __shared__ int s_rem;
  __shared__ float rsum[16];
  const int lane = tid & 63, wid = tid >> 6;

  if (K >= P_){
    float s = 0.f;
    for (int p = tid; p < P_; p += 1024) s += v[p];
    #pragma unroll
    for (int off = 32; off; off >>= 1) s += __shfl_down(s, off);
    if (lane == 0) rsum[wid] = s;
    __syncthreads();
    if (tid == 0){
      float t = 0.f;
      for (int w = 0; w < 16; ++w) t += rsum[w];
      atomicAdd(hard_acc, t);
    }
    return;
  }

  unsigned prefix = 0; int remaining = K;
  for (int shift = 24; shift >= 0; shift -= 8){
    #pragma unroll
    for (int j = 0; j < 4; ++j) histw[wid][lane * 4 + j] = 0;
    __syncthreads();
    unsigned hmask = (shift == 24) ? 0u : (0xFFFFFFFFu << (shift + 8));
    for (int p = tid; p < P_; p += 1024){
      unsigned u = __float_as_uint(v[p]);
      if ((u & hmask) == prefix) atomicAdd(&histw[wid][(u >> shift) & 255], 1);
    }
    __syncthreads();
    if (tid < 256){
      int s = 0;
      #pragma unroll
      for (int w = 0; w < 16; ++w) s += histw[w][tid];
      histT[tid] = s;
    }
    __syncthreads();
    if (wid == 0){
      int a0 = histT[lane*4+0], a1 = histT[lane*4+1],
          a2 = histT[lane*4+2], a3 = histT[lane*4+3];
      int tl = a0 + a1 + a2 + a3;
      int run = tl;
      #pragma unroll
      for (int off = 1; off < 64; off <<= 1){
        int x = __shfl_down(run, off);
        if (lane + off < 64) run += x;
      }
      int E  = run - tl;       // elements in bins above this lane's 4 bins
      int s3 = E;
      int s2 = s3 + a3;
      int s1 = s2 + a2;
      int s0 = s1 + a1;
      if (s0 < remaining && s0 + a0 >= remaining){ s_prefix = prefix | ((unsigned)(lane*4+0) << shift); s_rem = remaining - s0; }
      if (s1 < remaining && s1 + a1 >= remaining){ s_prefix = prefix | ((unsigned)(lane*4+1) << shift); s_rem = remaining - s1; }
      if (s2 < remaining && s2 + a2 >= remaining){ s_prefix = prefix | ((unsigned)(lane*4+2) << shift); s_rem = remaining - s2; }
      if (s3 < remaining && s3 + a3 >= remaining){ s_prefix = prefix | ((unsigned)(lane*4+3) << shift); s_rem = remaining - s3; }
    }
    __syncthreads();
    prefix = s_prefix;
    remaining = s_rem;
    __syncthreads();
  }

  float tv = __uint_as_float(prefix);
  float sgt = 0.f;
  for (int p = tid; p < P_; p += 1024){
    unsigned u = __float_as_uint(v[p]);
    if (u > prefix) sgt += v[p];
  }
  #pragma unroll
  for (int off = 32; off; off >>= 1) sgt += __shfl_down(sgt, off);
  if (lane == 0) rsum[wid] = sgt;
  __syncthreads();
  if (tid == 0){
    float s = 0.f;
    for (int w = 0; w < 16; ++w) s += rsum[w];
    atomicAdd(hard_acc, s + (float)remaining * tv);
  }
}

// ---------------- final combine ----------------
__global__ void k_final(const float* __restrict__ accs, const int* __restrict__ total_pos,
                        float* __restrict__ out){
  float tp = (float)(*total_pos);
  float conf = (accs[2] + accs[1]) / tp;
  float loc  = accs[0] / (tp * 4.0f);
  out[0] = conf + loc;
}

extern "C" void kernel_launch(void* const* d_in, const int* in_sizes, int n_in,
                              void* d_out, int out_size, void* d_ws, size_t ws_size,
                              hipStream_t stream){
  const float* pred_locs = (const float*)d_in[0];
  const float* scores    = (const float*)d_in[1];
  const float* boxes     = (const float*)d_in[2];
  const int*   labels    = (const int*)d_in[3];
  const float* priors    = (const float*)d_in[4];

  const size_t BP = (size_t)B_ * P_;
  char* w = (char*)d_ws;
  int*   true_classes = (int*)w;                              // BP int32
  float* ce_neg       = (float*)(w + BP * 4);                 // BP f32
  unsigned long long* packed = (unsigned long long*)(w + 2 * BP * 4);  // B*NOBJ u64
  int*   n_pos     = (int*)(w + 2 * BP * 4 + B_ * NOBJ_ * 8); // B int
  int*   total_pos = n_pos + B_;                              // 1 int
  float* accs      = (float*)(total_pos + 1);                 // [sl1, conf_pos, hard]

  k_init<<<4, 256, 0, stream>>>(packed, n_pos, total_pos, accs);

  dim3 g1(B_, 16);
  k_match1<<<g1, 256, 0, stream>>>(boxes, priors, packed);
  k_match2<<<g1, 256, 0, stream>>>(boxes, labels, priors, pred_locs, packed,
                                   true_classes, n_pos, total_pos, accs);

  // 256 rows per 64-thread block; BP = 1,572,096 = 6141 * 256 exactly
  k_ce<<<(int)(BP / 256), 64, 0, stream>>>(scores, true_classes, ce_neg, &accs[1]);

  k_topk<<<B_, 1024, 0, stream>>>(ce_neg, n_pos, &accs[2]);

  k_final<<<1, 1, 0, stream>>>(accs, total_pos, (float*)d_out);
}